// Round 1
// baseline (641.475 us; speedup 1.0000x reference)
//
#include <hip/hip_runtime.h>

#define NN 4096
#define DD 64
#define KK 5
#define TS 128
#define NBINS 2048
#define CAP (1u << 20)
#define RMED 8388607u  // (NN*NN - 1) / 2

struct Ctrl {
  unsigned gcount;   // gathered candidate count
  unsigned sel_bin;  // selected coarse bin
  unsigned rank;     // rank within selected bin (0-based)
  float median;
  float scales[KK];  // -kernel_scales[k] / median
};

// ---------------- norms ----------------
__global__ void norms_kernel(const float* __restrict__ x, const float* __restrict__ y,
                             float* __restrict__ xn, float* __restrict__ yn) {
  int r = blockIdx.x * blockDim.x + threadIdx.x;  // 0..8191
  const float* src = (r < NN) ? x : y;
  float* dst = (r < NN) ? xn : yn;
  int row = r & (NN - 1);
  const float4* p = (const float4*)(src + (size_t)row * DD);
  float s = 0.f;
#pragma unroll
  for (int i = 0; i < DD / 4; ++i) {
    float4 v = p[i];
    s = fmaf(v.x, v.x, s);
    s = fmaf(v.y, v.y, s);
    s = fmaf(v.z, v.z, s);
    s = fmaf(v.w, v.w, s);
  }
  dst[row] = s;
}

// ---------------- pair-tile kernel ----------------
// MODE 0: histogram xx into 2048 coarse bins
// MODE 1: gather xx values in ctrl->sel_bin into buf
// MODE 2: accumulate kernel sums (z=0: xx, z=1: yy, z=2: zz)
template <int MODE>
__global__ void __launch_bounds__(256)
pair_kernel(const float* __restrict__ x, const float* __restrict__ y,
            const float* __restrict__ xn, const float* __restrict__ yn,
            unsigned* __restrict__ hist, Ctrl* __restrict__ ctrl,
            float* __restrict__ buf, double* __restrict__ S) {
  __shared__ __align__(16) float lds[2 * DD * TS];  // 64KB
  __shared__ unsigned h[NBINS];                     // 8KB (used by MODE 0)
  float(*At)[TS] = (float(*)[TS])lds;
  float(*Bt)[TS] = (float(*)[TS])(lds + DD * TS);

  int t = threadIdx.x;
  int sel = (MODE == 2) ? blockIdx.z : 0;
  const float* A = (sel == 1) ? y : x;
  const float* B = (sel == 0) ? x : y;
  const float* An = (sel == 1) ? yn : xn;
  const float* Bn = (sel == 0) ? xn : yn;

  int rowBase = blockIdx.y * TS;
  int colBase = blockIdx.x * TS;

  if (MODE == 0) {
    for (int i = t; i < NBINS; i += 256) h[i] = 0;
  }

  // stage tiles transposed: At[k][r], Bt[k][c]
  {
    int r = t >> 1;
    int c0 = (t & 1) * 32;
    const float4* ga = (const float4*)(A + (size_t)(rowBase + r) * DD + c0);
    const float4* gb = (const float4*)(B + (size_t)(colBase + r) * DD + c0);
#pragma unroll
    for (int i = 0; i < 8; ++i) {
      float4 v = ga[i];
      int c = c0 + i * 4;
      At[c + 0][r] = v.x; At[c + 1][r] = v.y; At[c + 2][r] = v.z; At[c + 3][r] = v.w;
    }
#pragma unroll
    for (int i = 0; i < 8; ++i) {
      float4 v = gb[i];
      int c = c0 + i * 4;
      Bt[c + 0][r] = v.x; Bt[c + 1][r] = v.y; Bt[c + 2][r] = v.z; Bt[c + 3][r] = v.w;
    }
  }
  __syncthreads();

  int tx = t & 15, ty = t >> 4;
  int r0 = ty * 8, c0 = tx * 8;

  float acc[8][8] = {};
#pragma unroll 2
  for (int k = 0; k < DD; ++k) {
    float4 a0 = *(const float4*)&At[k][r0];
    float4 a1 = *(const float4*)&At[k][r0 + 4];
    float4 b0 = *(const float4*)&Bt[k][c0];
    float4 b1 = *(const float4*)&Bt[k][c0 + 4];
    float av[8] = {a0.x, a0.y, a0.z, a0.w, a1.x, a1.y, a1.z, a1.w};
    float bv[8] = {b0.x, b0.y, b0.z, b0.w, b1.x, b1.y, b1.z, b1.w};
#pragma unroll
    for (int i = 0; i < 8; ++i)
#pragma unroll
      for (int j = 0; j < 8; ++j) acc[i][j] = fmaf(av[i], bv[j], acc[i][j]);
  }

  float anr[8], bnr[8];
#pragma unroll
  for (int i = 0; i < 8; ++i) anr[i] = An[rowBase + r0 + i];
#pragma unroll
  for (int j = 0; j < 8; ++j) bnr[j] = Bn[colBase + c0 + j];

  // d[i][j] in place (identical expression in every MODE -> identical values)
#pragma unroll
  for (int i = 0; i < 8; ++i)
#pragma unroll
    for (int j = 0; j < 8; ++j) acc[i][j] = (anr[i] + bnr[j]) - 2.0f * acc[i][j];

  if (MODE == 0) {
    __syncthreads();  // h zeroed before first barrier; ensure compute done is not needed for h, but keep ordering simple
#pragma unroll
    for (int i = 0; i < 8; ++i)
#pragma unroll
      for (int j = 0; j < 8; ++j) {
        int b = (int)(acc[i][j] * 4.0f);
        b = min(max(b, 0), NBINS - 1);
        atomicAdd(&h[b], 1u);
      }
    __syncthreads();
    for (int i = t; i < NBINS; i += 256)
      if (h[i]) atomicAdd(&hist[i], h[i]);
  }

  if (MODE == 1) {
    unsigned sb = ctrl->sel_bin;
    __syncthreads();  // all tile reads done; reuse lds as match buffer
    __shared__ unsigned bcnt, gbase;
    if (t == 0) bcnt = 0;
    __syncthreads();
    float* mbuf = lds;
#pragma unroll
    for (int i = 0; i < 8; ++i)
#pragma unroll
      for (int j = 0; j < 8; ++j) {
        float d = acc[i][j];
        int b = (int)(d * 4.0f);
        b = min(max(b, 0), NBINS - 1);
        if ((unsigned)b == sb) {
          unsigned idx = atomicAdd(&bcnt, 1u);
          mbuf[idx] = d;  // max 16384 matches per block == lds capacity
        }
      }
    __syncthreads();
    if (t == 0) gbase = atomicAdd(&ctrl->gcount, bcnt);
    __syncthreads();
    for (unsigned i = t; i < bcnt; i += 256) {
      unsigned gi = gbase + i;
      if (gi < CAP) buf[gi] = mbuf[i];
    }
  }

  if (MODE == 2) {
    float sc[KK];
#pragma unroll
    for (int k = 0; k < KK; ++k) sc[k] = ctrl->scales[k];
    bool diagTile = (sel < 2) && (blockIdx.x == blockIdx.y);
    double s = 0.0;
#pragma unroll
    for (int i = 0; i < 8; ++i)
#pragma unroll
      for (int j = 0; j < 8; ++j) {
        float d = acc[i][j];
        float e = 0.f;
#pragma unroll
        for (int k = 0; k < KK; ++k) e += expf(d * sc[k]);
        bool skip = diagTile && (r0 + i == c0 + j);
        if (!skip) s += (double)e;
      }
    __syncthreads();  // done reading tiles; reuse lds for reduction
    double* red = (double*)lds;
    red[t] = s;
    __syncthreads();
    for (int off = 128; off > 0; off >>= 1) {
      if (t < off) red[t] += red[t + off];
      __syncthreads();
    }
    if (t == 0) atomicAdd(&S[sel], red[0]);
  }
}

// ---------------- find coarse bin of rank RMED ----------------
__global__ void select_bin_kernel(const unsigned* __restrict__ hist, Ctrl* __restrict__ ctrl) {
  if (threadIdx.x != 0 || blockIdx.x != 0) return;
  unsigned long long cum = 0;
  for (int b = 0; b < NBINS; ++b) {
    unsigned c = hist[b];
    if (cum + c > (unsigned long long)RMED) {
      ctrl->sel_bin = (unsigned)b;
      ctrl->rank = (unsigned)(RMED - cum);
      return;
    }
    cum += c;
  }
}

// ---------------- exact radix select among gathered candidates ----------------
__global__ void __launch_bounds__(256)
radix_select_kernel(Ctrl* __restrict__ ctrl, const float* __restrict__ buf,
                    const float* __restrict__ ksc) {
  __shared__ unsigned h[256];
  __shared__ unsigned spref, srank;
  int t = threadIdx.x;
  unsigned m = min(ctrl->gcount, CAP);
  if (t == 0) {
    spref = 0u;
    srank = ctrl->rank;
  }
  __syncthreads();

  for (int round = 0; round < 4; ++round) {
    int shift = 24 - 8 * round;
    h[t] = 0;
    __syncthreads();
    unsigned pref = spref;
    for (unsigned i = t; i < m; i += 256) {
      unsigned u = __float_as_uint(buf[i]);
      u ^= (u >> 31) ? 0xFFFFFFFFu : 0x80000000u;
      bool ok = (round == 0) ? true : (((u ^ pref) >> (shift + 8)) == 0u);
      if (ok) atomicAdd(&h[(u >> shift) & 255u], 1u);
    }
    __syncthreads();
    if (t == 0) {
      unsigned cum = 0, rank = srank;
      for (int b = 0; b < 256; ++b) {
        unsigned c = h[b];
        if (cum + c > rank) {
          spref = pref | ((unsigned)b << shift);
          srank = rank - cum;
          break;
        }
        cum += c;
      }
    }
    __syncthreads();
  }

  if (t == 0) {
    unsigned key = spref;
    unsigned u = (key & 0x80000000u) ? (key ^ 0x80000000u) : ~key;
    float med = __uint_as_float(u);
    ctrl->median = med;
    float base = -1.0f / med;
#pragma unroll
    for (int k = 0; k < KK; ++k) ctrl->scales[k] = base * ksc[k];
  }
}

// ---------------- finalize ----------------
__global__ void finalize_kernel(const double* __restrict__ S, float* __restrict__ out) {
  if (threadIdx.x == 0 && blockIdx.x == 0) {
    double offd = 1.0 / ((double)NN * (double)(NN - 1));
    double invK = 1.0 / (double)KK;
    double val = (S[0] + S[1]) * offd * invK - 2.0 * (S[2] * invK) / ((double)NN * (double)NN);
    out[0] = (float)val;
  }
}

extern "C" void kernel_launch(void* const* d_in, const int* in_sizes, int n_in,
                              void* d_out, int out_size, void* d_ws, size_t ws_size,
                              hipStream_t stream) {
  const float* x = (const float*)d_in[0];
  const float* y = (const float*)d_in[1];
  const float* ksc = (const float*)d_in[2];

  char* ws = (char*)d_ws;
  double* S = (double*)ws;                       // 3 doubles @ 0
  unsigned* hist = (unsigned*)(ws + 64);         // 2048 u32
  Ctrl* ctrl = (Ctrl*)(ws + 64 + 4 * NBINS);     // @ 8256
  float* xn = (float*)(ws + 8320);               // 4096 f32
  float* yn = xn + NN;                           // 4096 f32
  float* buf = (float*)(ws + 41088);             // CAP f32 (4MB)

  hipMemsetAsync(ws, 0, 8320, stream);  // S, hist, ctrl

  norms_kernel<<<32, 256, 0, stream>>>(x, y, xn, yn);
  pair_kernel<0><<<dim3(32, 32), 256, 0, stream>>>(x, y, xn, yn, hist, ctrl, buf, S);
  select_bin_kernel<<<1, 64, 0, stream>>>(hist, ctrl);
  pair_kernel<1><<<dim3(32, 32), 256, 0, stream>>>(x, y, xn, yn, hist, ctrl, buf, S);
  radix_select_kernel<<<1, 256, 0, stream>>>(ctrl, buf, ksc);
  pair_kernel<2><<<dim3(32, 32, 3), 256, 0, stream>>>(x, y, xn, yn, hist, ctrl, buf, S);
  finalize_kernel<<<1, 64, 0, stream>>>(S, (float*)d_out);
}

// Round 2
// 425.560 us; speedup vs baseline: 1.5074x; 1.5074x over previous
//
#include <hip/hip_runtime.h>

#define NN 4096
#define DD 64
#define KK 5
#define TS 128
#define NBINS 2048
#define CAP (1u << 20)
#define RMED 8388607u  // (NN*NN - 1) / 2

struct Ctrl {
  unsigned gcount;   // gathered candidate count
  unsigned sel_bin;  // selected coarse bin
  unsigned rank;     // rank (0-based) within selected bin
  unsigned spref;    // radix-select prefix (built over 4 rounds)
  unsigned srank;    // remaining rank within prefix
  float median;
  float scales[KK];  // -kernel_scales[k] / median
};

// ---------------- norms ----------------
__global__ void norms_kernel(const float* __restrict__ x, const float* __restrict__ y,
                             float* __restrict__ xn, float* __restrict__ yn) {
  int r = blockIdx.x * blockDim.x + threadIdx.x;  // 0..8191
  const float* src = (r < NN) ? x : y;
  float* dst = (r < NN) ? xn : yn;
  int row = r & (NN - 1);
  const float4* p = (const float4*)(src + (size_t)row * DD);
  float s = 0.f;
#pragma unroll
  for (int i = 0; i < DD / 4; ++i) {
    float4 v = p[i];
    s = fmaf(v.x, v.x, s);
    s = fmaf(v.y, v.y, s);
    s = fmaf(v.z, v.z, s);
    s = fmaf(v.w, v.w, s);
  }
  dst[row] = s;
}

// ---------------- pair-tile kernel ----------------
// MODE 0: histogram xx into 2048 coarse bins
// MODE 1: gather xx values in ctrl->sel_bin into buf
// MODE 2: accumulate kernel sums (z=0: xx, z=1: yy, z=2: zz)
template <int MODE>
__global__ void __launch_bounds__(256)
pair_kernel(const float* __restrict__ x, const float* __restrict__ y,
            const float* __restrict__ xn, const float* __restrict__ yn,
            unsigned* __restrict__ hist, Ctrl* __restrict__ ctrl,
            float* __restrict__ buf, double* __restrict__ S) {
  __shared__ __align__(16) float lds[2 * DD * TS];  // 64KB
  __shared__ unsigned h[NBINS];                     // 8KB (used by MODE 0)
  float(*At)[TS] = (float(*)[TS])lds;
  float(*Bt)[TS] = (float(*)[TS])(lds + DD * TS);

  int t = threadIdx.x;
  int sel = (MODE == 2) ? blockIdx.z : 0;
  const float* A = (sel == 1) ? y : x;
  const float* B = (sel == 0) ? x : y;
  const float* An = (sel == 1) ? yn : xn;
  const float* Bn = (sel == 0) ? xn : yn;

  int rowBase = blockIdx.y * TS;
  int colBase = blockIdx.x * TS;

  if (MODE == 0) {
    for (int i = t; i < NBINS; i += 256) h[i] = 0;
  }

  // stage tiles transposed: At[k][r], Bt[k][c]
  {
    int r = t >> 1;
    int c0 = (t & 1) * 32;
    const float4* ga = (const float4*)(A + (size_t)(rowBase + r) * DD + c0);
    const float4* gb = (const float4*)(B + (size_t)(colBase + r) * DD + c0);
#pragma unroll
    for (int i = 0; i < 8; ++i) {
      float4 v = ga[i];
      int c = c0 + i * 4;
      At[c + 0][r] = v.x; At[c + 1][r] = v.y; At[c + 2][r] = v.z; At[c + 3][r] = v.w;
    }
#pragma unroll
    for (int i = 0; i < 8; ++i) {
      float4 v = gb[i];
      int c = c0 + i * 4;
      Bt[c + 0][r] = v.x; Bt[c + 1][r] = v.y; Bt[c + 2][r] = v.z; Bt[c + 3][r] = v.w;
    }
  }
  __syncthreads();

  int tx = t & 15, ty = t >> 4;
  int r0 = ty * 8, c0 = tx * 8;

  float acc[8][8] = {};
#pragma unroll 2
  for (int k = 0; k < DD; ++k) {
    float4 a0 = *(const float4*)&At[k][r0];
    float4 a1 = *(const float4*)&At[k][r0 + 4];
    float4 b0 = *(const float4*)&Bt[k][c0];
    float4 b1 = *(const float4*)&Bt[k][c0 + 4];
    float av[8] = {a0.x, a0.y, a0.z, a0.w, a1.x, a1.y, a1.z, a1.w};
    float bv[8] = {b0.x, b0.y, b0.z, b0.w, b1.x, b1.y, b1.z, b1.w};
#pragma unroll
    for (int i = 0; i < 8; ++i)
#pragma unroll
      for (int j = 0; j < 8; ++j) acc[i][j] = fmaf(av[i], bv[j], acc[i][j]);
  }

  float anr[8], bnr[8];
#pragma unroll
  for (int i = 0; i < 8; ++i) anr[i] = An[rowBase + r0 + i];
#pragma unroll
  for (int j = 0; j < 8; ++j) bnr[j] = Bn[colBase + c0 + j];

  // d[i][j] in place (identical expression in MODE 0/1 -> identical values)
#pragma unroll
  for (int i = 0; i < 8; ++i)
#pragma unroll
    for (int j = 0; j < 8; ++j) acc[i][j] = (anr[i] + bnr[j]) - 2.0f * acc[i][j];

  if (MODE == 0) {
    __syncthreads();
#pragma unroll
    for (int i = 0; i < 8; ++i)
#pragma unroll
      for (int j = 0; j < 8; ++j) {
        int b = (int)(acc[i][j] * 4.0f);
        b = min(max(b, 0), NBINS - 1);
        atomicAdd(&h[b], 1u);
      }
    __syncthreads();
    for (int i = t; i < NBINS; i += 256)
      if (h[i]) atomicAdd(&hist[i], h[i]);
  }

  if (MODE == 1) {
    unsigned sb = ctrl->sel_bin;
    __syncthreads();  // all tile reads done; reuse lds as match buffer
    __shared__ unsigned bcnt, gbase;
    if (t == 0) bcnt = 0;
    __syncthreads();
    float* mbuf = lds;
#pragma unroll
    for (int i = 0; i < 8; ++i)
#pragma unroll
      for (int j = 0; j < 8; ++j) {
        float d = acc[i][j];
        int b = (int)(d * 4.0f);
        b = min(max(b, 0), NBINS - 1);
        if ((unsigned)b == sb) {
          unsigned idx = atomicAdd(&bcnt, 1u);
          mbuf[idx] = d;  // max 16384 matches per block == lds capacity
        }
      }
    __syncthreads();
    if (t == 0) gbase = atomicAdd(&ctrl->gcount, bcnt);
    __syncthreads();
    for (unsigned i = t; i < bcnt; i += 256) {
      unsigned gi = gbase + i;
      if (gi < CAP) buf[gi] = mbuf[i];
    }
  }

  if (MODE == 2) {
    float sc[KK];
#pragma unroll
    for (int k = 0; k < KK; ++k) sc[k] = ctrl->scales[k];
    bool diagTile = (sel < 2) && (blockIdx.x == blockIdx.y);
    double s = 0.0;
#pragma unroll
    for (int i = 0; i < 8; ++i)
#pragma unroll
      for (int j = 0; j < 8; ++j) {
        float d = acc[i][j];
        float e = 0.f;
#pragma unroll
        for (int k = 0; k < KK; ++k) e += expf(d * sc[k]);
        bool skip = diagTile && (r0 + i == c0 + j);
        if (!skip) s += (double)e;
      }
    __syncthreads();  // done reading tiles; reuse lds for reduction
    double* red = (double*)lds;
    red[t] = s;
    __syncthreads();
    for (int off = 128; off > 0; off >>= 1) {
      if (t < off) red[t] += red[t + off];
      __syncthreads();
    }
    if (t == 0) atomicAdd(&S[sel], red[0]);
  }
}

// ---------------- find coarse bin of rank RMED ----------------
__global__ void select_bin_kernel(const unsigned* __restrict__ hist, Ctrl* __restrict__ ctrl) {
  if (threadIdx.x != 0 || blockIdx.x != 0) return;
  unsigned long long cum = 0;
  for (int b = 0; b < NBINS; ++b) {
    unsigned c = hist[b];
    if (cum + c > (unsigned long long)RMED) {
      ctrl->sel_bin = (unsigned)b;
      ctrl->rank = (unsigned)(RMED - cum);
      return;
    }
    cum += c;
  }
}

// ---------------- parallel radix select: per-round histogram ----------------
__global__ void __launch_bounds__(256)
radix_hist_kernel(const Ctrl* __restrict__ ctrl, const float* __restrict__ buf,
                  unsigned* __restrict__ gh, int round) {
  __shared__ unsigned h[256];
  int t = threadIdx.x;
  h[t] = 0;
  __syncthreads();
  unsigned m = min(ctrl->gcount, CAP);
  int shift = 24 - 8 * round;
  unsigned pref = ctrl->spref;
  for (unsigned i = blockIdx.x * 256u + t; i < m; i += gridDim.x * 256u) {
    unsigned u = __float_as_uint(buf[i]);
    u ^= (u >> 31) ? 0xFFFFFFFFu : 0x80000000u;
    bool ok = (round == 0) || (((u ^ pref) >> (shift + 8)) == 0u);
    if (ok) atomicAdd(&h[(u >> shift) & 255u], 1u);
  }
  __syncthreads();
  if (h[t]) atomicAdd(&gh[round * 256 + t], h[t]);
}

// ---------------- parallel radix select: per-round bin scan ----------------
__global__ void radix_scan_kernel(Ctrl* __restrict__ ctrl, const unsigned* __restrict__ gh,
                                  const float* __restrict__ ksc, int round) {
  if (threadIdx.x != 0 || blockIdx.x != 0) return;
  int shift = 24 - 8 * round;
  unsigned rank = (round == 0) ? ctrl->rank : ctrl->srank;
  const unsigned* h = gh + round * 256;
  unsigned cum = 0;
  for (int b = 0; b < 256; ++b) {
    unsigned c = h[b];
    if (cum + c > rank) {
      ctrl->spref |= ((unsigned)b << shift);
      ctrl->srank = rank - cum;
      break;
    }
    cum += c;
  }
  if (round == 3) {
    unsigned key = ctrl->spref;
    unsigned u = (key & 0x80000000u) ? (key ^ 0x80000000u) : ~key;
    float med = __uint_as_float(u);
    ctrl->median = med;
    float base = -1.0f / med;
#pragma unroll
    for (int k = 0; k < KK; ++k) ctrl->scales[k] = base * ksc[k];
  }
}

// ---------------- finalize ----------------
__global__ void finalize_kernel(const double* __restrict__ S, float* __restrict__ out) {
  if (threadIdx.x == 0 && blockIdx.x == 0) {
    double offd = 1.0 / ((double)NN * (double)(NN - 1));
    double invK = 1.0 / (double)KK;
    double val = (S[0] + S[1]) * offd * invK - 2.0 * (S[2] * invK) / ((double)NN * (double)NN);
    out[0] = (float)val;
  }
}

extern "C" void kernel_launch(void* const* d_in, const int* in_sizes, int n_in,
                              void* d_out, int out_size, void* d_ws, size_t ws_size,
                              hipStream_t stream) {
  const float* x = (const float*)d_in[0];
  const float* y = (const float*)d_in[1];
  const float* ksc = (const float*)d_in[2];

  char* ws = (char*)d_ws;
  double* S = (double*)ws;                      // 3 doubles          @ 0
  unsigned* hist = (unsigned*)(ws + 64);        // 2048 u32           @ 64
  unsigned* gh = (unsigned*)(ws + 8256);        // 4*256 u32          @ 8256
  Ctrl* ctrl = (Ctrl*)(ws + 12352);             // ~48B               @ 12352
  float* xn = (float*)(ws + 12416);             // 4096 f32           @ 12416
  float* yn = xn + NN;                          // 4096 f32
  float* buf = (float*)(ws + 65536);            // CAP f32 (4MB)      @ 64K

  hipMemsetAsync(ws, 0, 12416, stream);  // S, hist, gh, ctrl

  norms_kernel<<<32, 256, 0, stream>>>(x, y, xn, yn);
  pair_kernel<0><<<dim3(32, 32), 256, 0, stream>>>(x, y, xn, yn, hist, ctrl, buf, S);
  select_bin_kernel<<<1, 64, 0, stream>>>(hist, ctrl);
  pair_kernel<1><<<dim3(32, 32), 256, 0, stream>>>(x, y, xn, yn, hist, ctrl, buf, S);
  for (int r = 0; r < 4; ++r) {
    radix_hist_kernel<<<96, 256, 0, stream>>>(ctrl, buf, gh, r);
    radix_scan_kernel<<<1, 64, 0, stream>>>(ctrl, gh, ksc, r);
  }
  pair_kernel<2><<<dim3(32, 32, 3), 256, 0, stream>>>(x, y, xn, yn, hist, ctrl, buf, S);
  finalize_kernel<<<1, 64, 0, stream>>>(S, (float*)d_out);
}

// Round 3
// 336.512 us; speedup vs baseline: 1.9062x; 1.2646x over previous
//
#include <hip/hip_runtime.h>

#define NN 4096
#define DD 64
#define KK 5
#define TS 128
#define NBINS 2048
#define CAP (1u << 20)
#define RMED 8388607u  // (NN*NN - 1) / 2

struct Ctrl {
  unsigned gcount;   // gathered candidate count
  unsigned sel_bin;  // selected coarse bin
  unsigned rank;     // rank (0-based) within selected bin
  unsigned spref;    // radix-select prefix (built over 4 rounds)
  unsigned srank;    // remaining rank within prefix
  unsigned use_pow;  // 1 if kernel_scales == [0.5,1,2,4,8]
  float median;
  float c2;          // base*0.5*log2(e) : u = exp2(d*c2), terms = u^{1,2,4,8,16}
  float scales[KK];  // base*kernel_scales[k] (general fallback)
};

__device__ inline float fast_exp2(float x) {
  float r;
  asm("v_exp_f32 %0, %1" : "=v"(r) : "v"(x));
  return r;
}

// ---------------- norms ----------------
__global__ void norms_kernel(const float* __restrict__ x, const float* __restrict__ y,
                             float* __restrict__ xn, float* __restrict__ yn) {
  int r = blockIdx.x * blockDim.x + threadIdx.x;  // 0..8191
  const float* src = (r < NN) ? x : y;
  float* dst = (r < NN) ? xn : yn;
  int row = r & (NN - 1);
  const float4* p = (const float4*)(src + (size_t)row * DD);
  float s = 0.f;
#pragma unroll
  for (int i = 0; i < DD / 4; ++i) {
    float4 v = p[i];
    s = fmaf(v.x, v.x, s);
    s = fmaf(v.y, v.y, s);
    s = fmaf(v.z, v.z, s);
    s = fmaf(v.w, v.w, s);
  }
  dst[row] = s;
}

// ---------------- pair-tile kernel ----------------
// MODE 0: histogram xx into 2048 coarse bins
// MODE 1: gather xx values in ctrl->sel_bin into buf
// MODE 2: accumulate kernel sums (z=0: xx, z=1: yy, z=2: zz)
template <int MODE>
__global__ void __launch_bounds__(256)
pair_kernel(const float* __restrict__ x, const float* __restrict__ y,
            const float* __restrict__ xn, const float* __restrict__ yn,
            unsigned* __restrict__ hist, Ctrl* __restrict__ ctrl,
            float* __restrict__ buf, double* __restrict__ S) {
  __shared__ __align__(16) float lds[2 * DD * TS];  // 64KB
  float(*At)[TS] = (float(*)[TS])lds;
  float(*Bt)[TS] = (float(*)[TS])(lds + DD * TS);

  int t = threadIdx.x;
  int sel = (MODE == 2) ? blockIdx.z : 0;
  const float* A = (sel == 1) ? y : x;
  const float* B = (sel == 0) ? x : y;
  const float* An = (sel == 1) ? yn : xn;
  const float* Bn = (sel == 0) ? xn : yn;

  int rowBase = blockIdx.y * TS;
  int colBase = blockIdx.x * TS;

  // stage tiles transposed: At[k][r], Bt[k][c]
  {
    int r = t >> 1;
    int c0 = (t & 1) * 32;
    const float4* ga = (const float4*)(A + (size_t)(rowBase + r) * DD + c0);
    const float4* gb = (const float4*)(B + (size_t)(colBase + r) * DD + c0);
#pragma unroll
    for (int i = 0; i < 8; ++i) {
      float4 v = ga[i];
      int c = c0 + i * 4;
      At[c + 0][r] = v.x; At[c + 1][r] = v.y; At[c + 2][r] = v.z; At[c + 3][r] = v.w;
    }
#pragma unroll
    for (int i = 0; i < 8; ++i) {
      float4 v = gb[i];
      int c = c0 + i * 4;
      Bt[c + 0][r] = v.x; Bt[c + 1][r] = v.y; Bt[c + 2][r] = v.z; Bt[c + 3][r] = v.w;
    }
  }
  __syncthreads();

  int tx = t & 15, ty = t >> 4;
  int r0 = ty * 8, c0 = tx * 8;

  float acc[8][8] = {};
  {
    const float* ap = &At[0][r0];
    const float* bp = &Bt[0][c0];
#pragma unroll 4
    for (int k = 0; k < DD; ++k) {
      float4 a0 = *(const float4*)(ap + k * TS);
      float4 a1 = *(const float4*)(ap + k * TS + 4);
      float4 b0 = *(const float4*)(bp + k * TS);
      float4 b1 = *(const float4*)(bp + k * TS + 4);
      float av[8] = {a0.x, a0.y, a0.z, a0.w, a1.x, a1.y, a1.z, a1.w};
      float bv[8] = {b0.x, b0.y, b0.z, b0.w, b1.x, b1.y, b1.z, b1.w};
#pragma unroll
      for (int i = 0; i < 8; ++i)
#pragma unroll
        for (int j = 0; j < 8; ++j) acc[i][j] = fmaf(av[i], bv[j], acc[i][j]);
    }
  }

  float anr[8], bnr[8];
#pragma unroll
  for (int i = 0; i < 8; ++i) anr[i] = An[rowBase + r0 + i];
#pragma unroll
  for (int j = 0; j < 8; ++j) bnr[j] = Bn[colBase + c0 + j];

  // d[i][j] in place (identical expression in MODE 0/1 -> identical values)
#pragma unroll
  for (int i = 0; i < 8; ++i)
#pragma unroll
    for (int j = 0; j < 8; ++j) acc[i][j] = (anr[i] + bnr[j]) - 2.0f * acc[i][j];

  if (MODE == 0) {
    __shared__ unsigned h[NBINS];  // 8KB, MODE-0-only (dead-stripped otherwise)
    for (int i = t; i < NBINS; i += 256) h[i] = 0;
    __syncthreads();
#pragma unroll
    for (int i = 0; i < 8; ++i)
#pragma unroll
      for (int j = 0; j < 8; ++j) {
        int b = (int)(acc[i][j] * 4.0f);
        b = min(max(b, 0), NBINS - 1);
        atomicAdd(&h[b], 1u);
      }
    __syncthreads();
    for (int i = t; i < NBINS; i += 256)
      if (h[i]) atomicAdd(&hist[i], h[i]);
  }

  if (MODE == 1) {
    unsigned sb = ctrl->sel_bin;
    __syncthreads();  // all tile reads done; reuse lds as match buffer
    __shared__ unsigned bcnt, gbase;
    if (t == 0) bcnt = 0;
    __syncthreads();
    float* mbuf = lds;
#pragma unroll
    for (int i = 0; i < 8; ++i)
#pragma unroll
      for (int j = 0; j < 8; ++j) {
        float d = acc[i][j];
        int b = (int)(d * 4.0f);
        b = min(max(b, 0), NBINS - 1);
        if ((unsigned)b == sb) {
          unsigned idx = atomicAdd(&bcnt, 1u);
          mbuf[idx] = d;  // max 16384 matches per block == lds capacity
        }
      }
    __syncthreads();
    if (t == 0) gbase = atomicAdd(&ctrl->gcount, bcnt);
    __syncthreads();
    for (unsigned i = t; i < bcnt; i += 256) {
      unsigned gi = gbase + i;
      if (gi < CAP) buf[gi] = mbuf[i];
    }
  }

  if (MODE == 2) {
    float s = 0.f;  // per-thread f32 partial (<=~350; error budget ok)
    if (ctrl->use_pow) {
      float c2 = ctrl->c2;
#pragma unroll
      for (int i = 0; i < 8; ++i)
#pragma unroll
        for (int j = 0; j < 8; ++j) {
          float u = fast_exp2(acc[i][j] * c2);  // exp(d*base*0.5)
          float u2 = u * u, u4 = u2 * u2, u8 = u4 * u4, u16 = u8 * u8;
          s += ((u + u2) + (u4 + u8)) + u16;
        }
    } else {
      float sc[KK];
#pragma unroll
      for (int k = 0; k < KK; ++k) sc[k] = ctrl->scales[k];
#pragma unroll
      for (int i = 0; i < 8; ++i)
#pragma unroll
        for (int j = 0; j < 8; ++j) {
          float e = 0.f;
#pragma unroll
          for (int k = 0; k < KK; ++k) e += expf(acc[i][j] * sc[k]);
          s += e;
        }
    }
    // diagonal handled analytically in finalize (exp(0)*5 per diag element)
    double sd = (double)s;
#pragma unroll
    for (int off = 32; off > 0; off >>= 1) sd += __shfl_down(sd, off);
    __shared__ double wsum[4];
    if ((t & 63) == 0) wsum[t >> 6] = sd;
    __syncthreads();
    if (t == 0) atomicAdd(&S[sel], (wsum[0] + wsum[1]) + (wsum[2] + wsum[3]));
  }
}

// ---------------- find coarse bin of rank RMED ----------------
__global__ void select_bin_kernel(const unsigned* __restrict__ hist, Ctrl* __restrict__ ctrl) {
  if (threadIdx.x != 0 || blockIdx.x != 0) return;
  unsigned long long cum = 0;
  for (int b = 0; b < NBINS; ++b) {
    unsigned c = hist[b];
    if (cum + c > (unsigned long long)RMED) {
      ctrl->sel_bin = (unsigned)b;
      ctrl->rank = (unsigned)(RMED - cum);
      return;
    }
    cum += c;
  }
}

// ---------------- parallel radix select: per-round histogram ----------------
__global__ void __launch_bounds__(256)
radix_hist_kernel(const Ctrl* __restrict__ ctrl, const float* __restrict__ buf,
                  unsigned* __restrict__ gh, int round) {
  __shared__ unsigned h[256];
  int t = threadIdx.x;
  h[t] = 0;
  __syncthreads();
  unsigned m = min(ctrl->gcount, CAP);
  int shift = 24 - 8 * round;
  unsigned pref = ctrl->spref;
  for (unsigned i = blockIdx.x * 256u + t; i < m; i += gridDim.x * 256u) {
    unsigned u = __float_as_uint(buf[i]);
    u ^= (u >> 31) ? 0xFFFFFFFFu : 0x80000000u;
    bool ok = (round == 0) || (((u ^ pref) >> (shift + 8)) == 0u);
    if (ok) atomicAdd(&h[(u >> shift) & 255u], 1u);
  }
  __syncthreads();
  if (h[t]) atomicAdd(&gh[round * 256 + t], h[t]);
}

// ---------------- parallel radix select: per-round bin scan ----------------
__global__ void radix_scan_kernel(Ctrl* __restrict__ ctrl, const unsigned* __restrict__ gh,
                                  const float* __restrict__ ksc, int round) {
  if (threadIdx.x != 0 || blockIdx.x != 0) return;
  int shift = 24 - 8 * round;
  unsigned rank = (round == 0) ? ctrl->rank : ctrl->srank;
  const unsigned* h = gh + round * 256;
  unsigned cum = 0;
  for (int b = 0; b < 256; ++b) {
    unsigned c = h[b];
    if (cum + c > rank) {
      ctrl->spref |= ((unsigned)b << shift);
      ctrl->srank = rank - cum;
      break;
    }
    cum += c;
  }
  if (round == 3) {
    unsigned key = ctrl->spref;
    unsigned u = (key & 0x80000000u) ? (key ^ 0x80000000u) : ~key;
    float med = __uint_as_float(u);
    ctrl->median = med;
    float base = -1.0f / med;
#pragma unroll
    for (int k = 0; k < KK; ++k) ctrl->scales[k] = base * ksc[k];
    ctrl->c2 = base * 0.5f * 1.44269504088896f;
    ctrl->use_pow = (ksc[0] == 0.5f && ksc[1] == 1.0f && ksc[2] == 2.0f &&
                     ksc[3] == 4.0f && ksc[4] == 8.0f) ? 1u : 0u;
  }
}

// ---------------- finalize ----------------
__global__ void finalize_kernel(const double* __restrict__ S, float* __restrict__ out) {
  if (threadIdx.x == 0 && blockIdx.x == 0) {
    // S[z] = sum over ALL pairs of sum_k exp(d*scale_k); diag of xx/yy contributes
    // exactly KK per element (d==0 -> exp(0)=1) -> subtract KK*NN analytically.
    double offd = 1.0 / ((double)NN * (double)(NN - 1));
    double invK = 1.0 / (double)KK;
    double kxx = (S[0] * invK) - (double)NN;
    double kyy = (S[1] * invK) - (double)NN;
    double kzz = S[2] * invK;
    double val = offd * (kxx + kyy) - 2.0 * kzz / ((double)NN * (double)NN);
    out[0] = (float)val;
  }
}

extern "C" void kernel_launch(void* const* d_in, const int* in_sizes, int n_in,
                              void* d_out, int out_size, void* d_ws, size_t ws_size,
                              hipStream_t stream) {
  const float* x = (const float*)d_in[0];
  const float* y = (const float*)d_in[1];
  const float* ksc = (const float*)d_in[2];

  char* ws = (char*)d_ws;
  double* S = (double*)ws;                      // 3 doubles          @ 0
  unsigned* hist = (unsigned*)(ws + 64);        // 2048 u32           @ 64
  unsigned* gh = (unsigned*)(ws + 8256);        // 4*256 u32          @ 8256
  Ctrl* ctrl = (Ctrl*)(ws + 12352);             // ~64B               @ 12352
  float* xn = (float*)(ws + 12480);             // 4096 f32
  float* yn = xn + NN;                          // 4096 f32
  float* buf = (float*)(ws + 65536);            // CAP f32 (4MB)      @ 64K

  hipMemsetAsync(ws, 0, 12480, stream);  // S, hist, gh, ctrl

  norms_kernel<<<32, 256, 0, stream>>>(x, y, xn, yn);
  pair_kernel<0><<<dim3(32, 32), 256, 0, stream>>>(x, y, xn, yn, hist, ctrl, buf, S);
  select_bin_kernel<<<1, 64, 0, stream>>>(hist, ctrl);
  pair_kernel<1><<<dim3(32, 32), 256, 0, stream>>>(x, y, xn, yn, hist, ctrl, buf, S);
  for (int r = 0; r < 4; ++r) {
    radix_hist_kernel<<<96, 256, 0, stream>>>(ctrl, buf, gh, r);
    radix_scan_kernel<<<1, 64, 0, stream>>>(ctrl, gh, ksc, r);
  }
  pair_kernel<2><<<dim3(32, 32, 3), 256, 0, stream>>>(x, y, xn, yn, hist, ctrl, buf, S);
  finalize_kernel<<<1, 64, 0, stream>>>(S, (float*)d_out);
}

// Round 4
// 265.995 us; speedup vs baseline: 2.4116x; 1.2651x over previous
//
#include <hip/hip_runtime.h>

#define NN 4096
#define DD 64
#define KK 5
#define TS 128
#define KH 32          // k-dims staged per phase (2 phases of 32 = DD)
#define NBINS 1024
#define BINMUL 2.0f    // bin width 0.5 over [0, 512)
#define CAP (1u << 20)
#define RMED 8388607u  // (NN*NN - 1) / 2

struct Ctrl {
  unsigned gcount;   // gathered candidate count
  unsigned sel_bin;  // selected coarse bin
  unsigned rank;     // rank (0-based) within selected bin
  unsigned spref;    // radix-select prefix (built over 4 rounds)
  unsigned srank;    // remaining rank within prefix
  unsigned use_pow;  // 1 if kernel_scales == [0.5,1,2,4,8]
  float median;
  float c2;          // base*0.5*log2(e) : u = exp2(d*c2), terms = u^{1,2,4,8,16}
  float scales[KK];  // base*kernel_scales[k] (general fallback)
};

__device__ inline float fast_exp2(float x) {
  float r;
  asm("v_exp_f32 %0, %1" : "=v"(r) : "v"(x));
  return r;
}

__device__ inline int swz4(int f) {  // float4-slot XOR swizzle -> float offset
  return (f ^ (f >> 3)) << 2;
}

// ---------------- norms ----------------
__global__ void norms_kernel(const float* __restrict__ x, const float* __restrict__ y,
                             float* __restrict__ xn, float* __restrict__ yn) {
  int r = blockIdx.x * blockDim.x + threadIdx.x;  // 0..8191
  const float* src = (r < NN) ? x : y;
  float* dst = (r < NN) ? xn : yn;
  int row = r & (NN - 1);
  const float4* p = (const float4*)(src + (size_t)row * DD);
  float s = 0.f;
#pragma unroll
  for (int i = 0; i < DD / 4; ++i) {
    float4 v = p[i];
    s = fmaf(v.x, v.x, s);
    s = fmaf(v.y, v.y, s);
    s = fmaf(v.z, v.z, s);
    s = fmaf(v.w, v.w, s);
  }
  dst[row] = s;
}

// ---------------- pair-tile kernel ----------------
// MODE 0: histogram xx into NBINS coarse bins
// MODE 1: gather xx values in ctrl->sel_bin into buf
// MODE 2: accumulate kernel sums (z=0: xx, z=1: yy, z=2: zz)
template <int MODE>
__global__ void __launch_bounds__(256, 4)
pair_kernel(const float* __restrict__ x, const float* __restrict__ y,
            const float* __restrict__ xn, const float* __restrict__ yn,
            unsigned* __restrict__ hist, Ctrl* __restrict__ ctrl,
            float* __restrict__ buf, double* __restrict__ S) {
  __shared__ __align__(16) float As[KH * TS];  // 16KB, swizzled [k][r]
  __shared__ __align__(16) float Bs[KH * TS];  // 16KB, swizzled [k][c]

  int t = threadIdx.x;
  int sel = (MODE == 2) ? blockIdx.z : 0;
  const float* A = (sel == 1) ? y : x;
  const float* B = (sel == 0) ? x : y;
  const float* An = (sel == 1) ? yn : xn;
  const float* Bn = (sel == 0) ? xn : yn;

  int rowBase = blockIdx.y * TS;
  int colBase = blockIdx.x * TS;

  // fragment read pointers (swizzled float4 slots; constant across k)
  int tx = t & 15, ty = t >> 4;
  int r0 = ty * 8, c0 = tx * 8;
  const float* a0p = As + swz4(r0 >> 2);
  const float* a1p = As + swz4((r0 >> 2) + 1);
  const float* b0p = Bs + swz4(c0 >> 2);
  const float* b1p = Bs + swz4((c0 >> 2) + 1);

  // staging assignment: threads 0..127 -> A rows, 128..255 -> B rows
  int tile = t >> 7;
  int r = t & 127;
  const float* srow = (tile ? B : A) + (size_t)((tile ? colBase : rowBase) + r) * DD;
  float* dbuf = tile ? Bs : As;
  int woff = swz4(r >> 2) | (r & 3);

  float acc[8][8] = {};
#pragma unroll
  for (int p = 0; p < 2; ++p) {
    float4 v[8];
#pragma unroll
    for (int i = 0; i < 8; ++i) v[i] = *(const float4*)(srow + p * KH + i * 4);
    if (p) __syncthreads();  // wait until everyone finished reading phase p-1
#pragma unroll
    for (int i = 0; i < 8; ++i) {
      int k = i * 4;
      dbuf[(k + 0) * TS + woff] = v[i].x;
      dbuf[(k + 1) * TS + woff] = v[i].y;
      dbuf[(k + 2) * TS + woff] = v[i].z;
      dbuf[(k + 3) * TS + woff] = v[i].w;
    }
    __syncthreads();
#pragma unroll 4
    for (int k = 0; k < KH; ++k) {
      float4 a0 = *(const float4*)(a0p + k * TS);
      float4 a1 = *(const float4*)(a1p + k * TS);
      float4 b0 = *(const float4*)(b0p + k * TS);
      float4 b1 = *(const float4*)(b1p + k * TS);
      float av[8] = {a0.x, a0.y, a0.z, a0.w, a1.x, a1.y, a1.z, a1.w};
      float bv[8] = {b0.x, b0.y, b0.z, b0.w, b1.x, b1.y, b1.z, b1.w};
#pragma unroll
      for (int i = 0; i < 8; ++i)
#pragma unroll
        for (int j = 0; j < 8; ++j) acc[i][j] = fmaf(av[i], bv[j], acc[i][j]);
    }
  }

  float anr[8], bnr[8];
#pragma unroll
  for (int i = 0; i < 8; ++i) anr[i] = An[rowBase + r0 + i];
#pragma unroll
  for (int j = 0; j < 8; ++j) bnr[j] = Bn[colBase + c0 + j];

  // d[i][j] in place (identical expression in MODE 0/1 -> identical values)
#pragma unroll
  for (int i = 0; i < 8; ++i)
#pragma unroll
    for (int j = 0; j < 8; ++j) acc[i][j] = (anr[i] + bnr[j]) - 2.0f * acc[i][j];

  if (MODE == 0) {
    __shared__ unsigned h[NBINS];  // 4KB
    for (int i = t; i < NBINS; i += 256) h[i] = 0;
    __syncthreads();
#pragma unroll
    for (int i = 0; i < 8; ++i)
#pragma unroll
      for (int j = 0; j < 8; ++j) {
        int b = (int)(acc[i][j] * BINMUL);
        b = min(max(b, 0), NBINS - 1);
        atomicAdd(&h[b], 1u);
      }
    __syncthreads();
    for (int i = t; i < NBINS; i += 256)
      if (h[i]) atomicAdd(&hist[i], h[i]);
  }

  if (MODE == 1) {
    unsigned sb = ctrl->sel_bin;
    __syncthreads();  // all tile reads done; reuse As as match buffer
    __shared__ unsigned bcnt, gbase;
    if (t == 0) bcnt = 0;
    __syncthreads();
    float* mbuf = As;  // 4096 floats capacity
#pragma unroll
    for (int i = 0; i < 8; ++i)
#pragma unroll
      for (int j = 0; j < 8; ++j) {
        float d = acc[i][j];
        int b = (int)(d * BINMUL);
        b = min(max(b, 0), NBINS - 1);
        if ((unsigned)b == sb) {
          unsigned idx = atomicAdd(&bcnt, 1u);
          if (idx < (unsigned)(KH * TS)) mbuf[idx] = d;
        }
      }
    __syncthreads();
    unsigned cnt = min(bcnt, (unsigned)(KH * TS));
    if (t == 0) gbase = atomicAdd(&ctrl->gcount, cnt);
    __syncthreads();
    for (unsigned i = t; i < cnt; i += 256) {
      unsigned gi = gbase + i;
      if (gi < CAP) buf[gi] = mbuf[i];
    }
  }

  if (MODE == 2) {
    float s = 0.f;  // per-thread f32 partial
    if (ctrl->use_pow) {
      float c2 = ctrl->c2;
#pragma unroll
      for (int i = 0; i < 8; ++i)
#pragma unroll
        for (int j = 0; j < 8; ++j) {
          float u = fast_exp2(acc[i][j] * c2);  // exp(d*base*0.5)
          float u2 = u * u, u4 = u2 * u2, u8 = u4 * u4, u16 = u8 * u8;
          s += ((u + u2) + (u4 + u8)) + u16;
        }
    } else {
      float sc[KK];
#pragma unroll
      for (int k = 0; k < KK; ++k) sc[k] = ctrl->scales[k];
#pragma unroll
      for (int i = 0; i < 8; ++i)
#pragma unroll
        for (int j = 0; j < 8; ++j) {
          float e = 0.f;
#pragma unroll
          for (int k = 0; k < KK; ++k) e += expf(acc[i][j] * sc[k]);
          s += e;
        }
    }
    // diagonal handled analytically in finalize (exp(0)*KK per diag element)
    double sd = (double)s;
#pragma unroll
    for (int off = 32; off > 0; off >>= 1) sd += __shfl_down(sd, off);
    __shared__ double wsum[4];
    if ((t & 63) == 0) wsum[t >> 6] = sd;
    __syncthreads();
    if (t == 0) atomicAdd(&S[sel], (wsum[0] + wsum[1]) + (wsum[2] + wsum[3]));
  }
}

// ---------------- find coarse bin of rank RMED (parallel scan) ----------------
__global__ void __launch_bounds__(256)
select_bin_kernel(const unsigned* __restrict__ hist, Ctrl* __restrict__ ctrl) {
  __shared__ unsigned ps[256];
  int t = threadIdx.x;
  unsigned loc[NBINS / 256];
  unsigned s = 0;
#pragma unroll
  for (int i = 0; i < NBINS / 256; ++i) {
    loc[i] = hist[t * (NBINS / 256) + i];
    s += loc[i];
  }
  ps[t] = s;
  __syncthreads();
  for (int off = 1; off < 256; off <<= 1) {
    unsigned v = ps[t];
    unsigned add = (t >= off) ? ps[t - off] : 0u;
    __syncthreads();
    ps[t] = v + add;
    __syncthreads();
  }
  unsigned incl = ps[t], excl = incl - s;
  if (RMED >= excl && RMED < incl) {
    unsigned rank = RMED - excl;
#pragma unroll
    for (int i = 0; i < NBINS / 256; ++i) {
      if (rank < loc[i]) {
        ctrl->sel_bin = (unsigned)(t * (NBINS / 256) + i);
        ctrl->rank = rank;
        break;
      }
      rank -= loc[i];
    }
  }
}

// ---------------- parallel radix select: per-round histogram ----------------
__global__ void __launch_bounds__(256)
radix_hist_kernel(const Ctrl* __restrict__ ctrl, const float* __restrict__ buf,
                  unsigned* __restrict__ gh, int round) {
  __shared__ unsigned h[256];
  int t = threadIdx.x;
  h[t] = 0;
  __syncthreads();
  unsigned m = min(ctrl->gcount, CAP);
  int shift = 24 - 8 * round;
  unsigned pref = ctrl->spref;
  for (unsigned i = blockIdx.x * 256u + t; i < m; i += gridDim.x * 256u) {
    unsigned u = __float_as_uint(buf[i]);
    u ^= (u >> 31) ? 0xFFFFFFFFu : 0x80000000u;
    bool ok = (round == 0) || (((u ^ pref) >> (shift + 8)) == 0u);
    if (ok) atomicAdd(&h[(u >> shift) & 255u], 1u);
  }
  __syncthreads();
  if (h[t]) atomicAdd(&gh[round * 256 + t], h[t]);
}

// ---------------- parallel radix select: per-round bin scan ----------------
__global__ void __launch_bounds__(256)
radix_scan_kernel(Ctrl* __restrict__ ctrl, const unsigned* __restrict__ gh,
                  const float* __restrict__ ksc, int round) {
  __shared__ unsigned ps[256];
  int t = threadIdx.x;
  unsigned rank = (round == 0) ? ctrl->rank : ctrl->srank;
  unsigned c = gh[round * 256 + t];
  ps[t] = c;
  __syncthreads();
  for (int off = 1; off < 256; off <<= 1) {
    unsigned v = ps[t];
    unsigned add = (t >= off) ? ps[t - off] : 0u;
    __syncthreads();
    ps[t] = v + add;
    __syncthreads();
  }
  unsigned incl = ps[t], excl = incl - c;
  if (rank >= excl && rank < incl) {
    int shift = 24 - 8 * round;
    unsigned np = ctrl->spref | ((unsigned)t << shift);
    ctrl->spref = np;
    ctrl->srank = rank - excl;
    if (round == 3) {
      unsigned u = (np & 0x80000000u) ? (np ^ 0x80000000u) : ~np;
      float med = __uint_as_float(u);
      ctrl->median = med;
      float base = -1.0f / med;
#pragma unroll
      for (int k = 0; k < KK; ++k) ctrl->scales[k] = base * ksc[k];
      ctrl->c2 = base * 0.5f * 1.44269504088896f;
      ctrl->use_pow = (ksc[0] == 0.5f && ksc[1] == 1.0f && ksc[2] == 2.0f &&
                       ksc[3] == 4.0f && ksc[4] == 8.0f) ? 1u : 0u;
    }
  }
}

// ---------------- finalize ----------------
__global__ void finalize_kernel(const double* __restrict__ S, float* __restrict__ out) {
  if (threadIdx.x == 0 && blockIdx.x == 0) {
    double offd = 1.0 / ((double)NN * (double)(NN - 1));
    double invK = 1.0 / (double)KK;
    double kxx = (S[0] * invK) - (double)NN;  // subtract diagonal (exp(0)=1, KK terms)
    double kyy = (S[1] * invK) - (double)NN;
    double kzz = S[2] * invK;
    double val = offd * (kxx + kyy) - 2.0 * kzz / ((double)NN * (double)NN);
    out[0] = (float)val;
  }
}

extern "C" void kernel_launch(void* const* d_in, const int* in_sizes, int n_in,
                              void* d_out, int out_size, void* d_ws, size_t ws_size,
                              hipStream_t stream) {
  const float* x = (const float*)d_in[0];
  const float* y = (const float*)d_in[1];
  const float* ksc = (const float*)d_in[2];

  char* ws = (char*)d_ws;
  double* S = (double*)ws;                      // 3 doubles          @ 0
  unsigned* hist = (unsigned*)(ws + 64);        // NBINS u32          @ 64
  unsigned* gh = (unsigned*)(ws + 64 + 4 * NBINS);  // 4*256 u32
  Ctrl* ctrl = (Ctrl*)(ws + 64 + 4 * NBINS + 4096); // ~64B
  float* xn = (float*)(ws + 16384);             // 4096 f32
  float* yn = xn + NN;                          // 4096 f32
  float* buf = (float*)(ws + 65536);            // CAP f32 (4MB)      @ 64K

  hipMemsetAsync(ws, 0, 16384 + 8 * NN, stream);  // S, hist, gh, ctrl (+norms area)

  norms_kernel<<<32, 256, 0, stream>>>(x, y, xn, yn);
  pair_kernel<0><<<dim3(32, 32), 256, 0, stream>>>(x, y, xn, yn, hist, ctrl, buf, S);
  select_bin_kernel<<<1, 256, 0, stream>>>(hist, ctrl);
  pair_kernel<1><<<dim3(32, 32), 256, 0, stream>>>(x, y, xn, yn, hist, ctrl, buf, S);
  for (int r = 0; r < 4; ++r) {
    radix_hist_kernel<<<96, 256, 0, stream>>>(ctrl, buf, gh, r);
    radix_scan_kernel<<<1, 256, 0, stream>>>(ctrl, gh, ksc, r);
  }
  pair_kernel<2><<<dim3(32, 32, 3), 256, 0, stream>>>(x, y, xn, yn, hist, ctrl, buf, S);
  finalize_kernel<<<1, 64, 0, stream>>>(S, (float*)d_out);
}